// Round 1
// baseline (26.686 us; speedup 1.0000x reference)
//
#include <hip/hip_runtime.h>

#define POOL  7
#define CH    512
#define IMG_H 256
#define IMG_W 256

__global__ void __launch_bounds__(128)
roi_align_kernel(const float* __restrict__ img,
                 const int* __restrict__ rois,
                 float* __restrict__ out)
{
    const int bid = blockIdx.x;            // (roi, py, px)
    const int px  = bid % POOL;
    const int py  = (bid / POOL) % POOL;
    const int r   = bid / (POOL * POOL);

    const int x = rois[r * 4 + 0];
    const int y = rois[r * 4 + 1];
    const int w = rois[r * 4 + 2];
    const int h = rois[r * 4 + 3];

    // x-axis coords (mirror reference: floor, trunc-cast, clip to [0,size-1], +start, clip to [0,full-1])
    const float fx  = (px + 0.5f) * (float)w / (float)POOL - 0.5f;
    const float fx0 = floorf(fx);
    const float tx  = fx - fx0;
    const int   ifx = (int)fx0;
    const int   x0  = min(max(min(max(ifx,     0), w - 1) + x, 0), IMG_W - 1);
    const int   x1  = min(max(min(max(ifx + 1, 0), w - 1) + x, 0), IMG_W - 1);

    // y-axis coords
    const float fy  = (py + 0.5f) * (float)h / (float)POOL - 0.5f;
    const float fy0 = floorf(fy);
    const float ty  = fy - fy0;
    const int   ify = (int)fy0;
    const int   y0  = min(max(min(max(ify,     0), h - 1) + y, 0), IMG_H - 1);
    const int   y1  = min(max(min(max(ify + 1, 0), h - 1) + y, 0), IMG_H - 1);

    const float4* tl = (const float4*)(img + ((size_t)y0 * IMG_W + x0) * CH);
    const float4* tr = (const float4*)(img + ((size_t)y0 * IMG_W + x1) * CH);
    const float4* bl = (const float4*)(img + ((size_t)y1 * IMG_W + x0) * CH);
    const float4* br = (const float4*)(img + ((size_t)y1 * IMG_W + x1) * CH);

    const int c4 = threadIdx.x;            // 0..127, one float4 (4 channels) per thread

    const float4 a = tl[c4];
    const float4 b = tr[c4];
    const float4 c = bl[c4];
    const float4 d = br[c4];

    float4 res;
    {
        // top = a + (b-a)*tx ; bot = c + (d-c)*tx ; res = top + (bot-top)*ty
        float tpx = a.x + (b.x - a.x) * tx;
        float tpy = a.y + (b.y - a.y) * tx;
        float tpz = a.z + (b.z - a.z) * tx;
        float tpw = a.w + (b.w - a.w) * tx;
        float btx = c.x + (d.x - c.x) * tx;
        float bty = c.y + (d.y - c.y) * tx;
        float btz = c.z + (d.z - c.z) * tx;
        float btw = c.w + (d.w - c.w) * tx;
        res.x = tpx + (btx - tpx) * ty;
        res.y = tpy + (bty - tpy) * ty;
        res.z = tpz + (btz - tpz) * ty;
        res.w = tpw + (btw - tpw) * ty;
    }

    float4* o = (float4*)(out + (size_t)bid * CH);
    o[c4] = res;
}

extern "C" void kernel_launch(void* const* d_in, const int* in_sizes, int n_in,
                              void* d_out, int out_size, void* d_ws, size_t ws_size,
                              hipStream_t stream)
{
    const float* img  = (const float*)d_in[0];
    const int*   rois = (const int*)d_in[1];
    float*       out  = (float*)d_out;

    const int n_rois  = in_sizes[1] / 4;   // 300
    const int nblocks = n_rois * POOL * POOL;

    roi_align_kernel<<<nblocks, 128, 0, stream>>>(img, rois, out);
}

// Round 3
// 26.397 us; speedup vs baseline: 1.0109x; 1.0109x over previous
//
#include <hip/hip_runtime.h>

#define POOL  7
#define CH    512
#define IMG_H 256
#define IMG_W 256

typedef float f32x4 __attribute__((ext_vector_type(4)));

// One block per (roi, py). 256 threads: c4 = tid&127 selects the float4
// channel group, half = tid>>7 selects px parity. Each thread computes
// 3-4 pool cells -> 12-16 independent global loads in flight.
__global__ void __launch_bounds__(256)
roi_align_kernel(const float* __restrict__ img,
                 const int* __restrict__ rois,
                 float* __restrict__ out)
{
    const int bid = blockIdx.x;            // (roi, py)
    const int py  = bid % POOL;
    const int r   = bid / POOL;

    const int x = rois[r * 4 + 0];
    const int y = rois[r * 4 + 1];
    const int w = rois[r * 4 + 2];
    const int h = rois[r * 4 + 3];

    // y-axis coords (mirror reference exactly)
    const float fy  = (py + 0.5f) * (float)h / (float)POOL - 0.5f;
    const float fy0 = floorf(fy);
    const float ty  = fy - fy0;
    const int   ify = (int)fy0;
    const int   y0  = min(max(min(max(ify,     0), h - 1) + y, 0), IMG_H - 1);
    const int   y1  = min(max(min(max(ify + 1, 0), h - 1) + y, 0), IMG_H - 1);

    const int c4   = threadIdx.x & 127;    // float4 index within 512 channels
    const int half = threadIdx.x >> 7;     // 0 or 1 (wave-uniform)

    const float* row0 = img + (size_t)y0 * IMG_W * CH;
    const float* row1 = img + (size_t)y1 * IMG_W * CH;

    f32x4 A[4], B[4], C[4], D[4];
    float txs[4];

    // Pass 1: addresses + loads (all independent, compiler schedules them early)
    #pragma unroll
    for (int k = 0; k < 4; ++k) {
        const int px = half + 2 * k;
        if (px < POOL) {
            const float fx  = (px + 0.5f) * (float)w / (float)POOL - 0.5f;
            const float fx0 = floorf(fx);
            txs[k] = fx - fx0;
            const int ifx = (int)fx0;
            const int x0  = min(max(min(max(ifx,     0), w - 1) + x, 0), IMG_W - 1);
            const int x1  = min(max(min(max(ifx + 1, 0), w - 1) + x, 0), IMG_W - 1);
            A[k] = *(const f32x4*)(row0 + (size_t)x0 * CH + c4 * 4);
            B[k] = *(const f32x4*)(row0 + (size_t)x1 * CH + c4 * 4);
            C[k] = *(const f32x4*)(row1 + (size_t)x0 * CH + c4 * 4);
            D[k] = *(const f32x4*)(row1 + (size_t)x1 * CH + c4 * 4);
        }
    }

    // Pass 2: blend + store (non-temporal: don't evict image from L2)
    #pragma unroll
    for (int k = 0; k < 4; ++k) {
        const int px = half + 2 * k;
        if (px < POOL) {
            const float tx = txs[k];
            const f32x4 a = A[k], b = B[k], c = C[k], d = D[k];
            const f32x4 top = a + (b - a) * tx;
            const f32x4 bot = c + (d - c) * tx;
            const f32x4 res = top + (bot - top) * ty;

            f32x4* o = (f32x4*)(out + ((size_t)(r * POOL * POOL + py * POOL + px)) * CH);
            __builtin_nontemporal_store(res, o + c4);
        }
    }
}

extern "C" void kernel_launch(void* const* d_in, const int* in_sizes, int n_in,
                              void* d_out, int out_size, void* d_ws, size_t ws_size,
                              hipStream_t stream)
{
    const float* img  = (const float*)d_in[0];
    const int*   rois = (const int*)d_in[1];
    float*       out  = (float*)d_out;

    const int n_rois  = in_sizes[1] / 4;   // 300
    const int nblocks = n_rois * POOL;     // one block per (roi, py)

    roi_align_kernel<<<nblocks, 256, 0, stream>>>(img, rois, out);
}